// Round 1
// baseline (98.816 us; speedup 1.0000x reference)
//
#include <hip/hip_runtime.h>

#define MARGIN_F 0.5f
#define EPS_F 1e-12f

// One wave (64 lanes) per row. Each lane reads 2 float4 per array:
//   float4 index lane       -> floats [4*lane,   4*lane+4)      (first 256 floats)
//   float4 index lane + 64  -> floats [256+4*lane, 256+4*lane+4) (second 256 floats)
// Both loads are fully coalesced (64 lanes x 16B = 1 KB contiguous per instr).
__global__ __launch_bounds__(256, 8) void triplet_partial(
    const float* __restrict__ targets,
    const float* __restrict__ preds,
    float* __restrict__ partial,
    int n_rows)
{
    const int lane = threadIdx.x & 63;
    const int wid  = threadIdx.x >> 6;            // wave index within block (0..3)
    const int gwave  = blockIdx.x * 4 + wid;
    const int nwaves = gridDim.x * 4;

    float acc = 0.0f;
    for (int row = gwave; row < n_rows; row += nwaves) {
        const float4* t4 = reinterpret_cast<const float4*>(targets) + (size_t)row * 128;
        const float4* p4 = reinterpret_cast<const float4*>(preds)   + (size_t)row * 128;

        float4 ta = t4[lane];
        float4 tb = t4[lane + 64];
        float4 pa = p4[lane];
        float4 pb = p4[lane + 64];

        float pp = pa.x*pa.x + pa.y*pa.y + pa.z*pa.z + pa.w*pa.w
                 + pb.x*pb.x + pb.y*pb.y + pb.z*pb.z + pb.w*pb.w;
        float tt = ta.x*ta.x + ta.y*ta.y + ta.z*ta.z + ta.w*ta.w
                 + tb.x*tb.x + tb.y*tb.y + tb.z*tb.z + tb.w*tb.w;
        float pt = pa.x*ta.x + pa.y*ta.y + pa.z*ta.z + pa.w*ta.w
                 + pb.x*tb.x + pb.y*tb.y + pb.z*tb.z + pb.w*tb.w;

        // Wave-wide reduction of the three scalars (64 lanes -> all lanes hold sum).
        #pragma unroll
        for (int off = 32; off > 0; off >>= 1) {
            pp += __shfl_xor(pp, off, 64);
            tt += __shfl_xor(tt, off, 64);
            pt += __shfl_xor(pt, off, 64);
        }

        float sim  = pt;
        float pt2  = pt * pt;
        float num  = pp - pt2;                          // preds . neg_unnorm
        float n2   = fmaxf(pp - 2.0f * pt2 + pt2 * tt, 0.0f);  // ||neg_unnorm||^2
        float nrm  = fmaxf(sqrtf(n2), EPS_F);
        float spn  = num / nrm;                         // sim_pred_neg
        float loss = fmaxf(MARGIN_F + spn - sim, 0.0f);

        if (lane == 0) acc += loss;
    }

    __shared__ float wsum[4];
    if (lane == 0) wsum[wid] = acc;
    __syncthreads();
    if (threadIdx.x == 0) {
        partial[blockIdx.x] = (wsum[0] + wsum[1]) + (wsum[2] + wsum[3]);
    }
}

// Deterministic single-block finish: fixed strided accumulation + fixed tree.
__global__ __launch_bounds__(256) void triplet_final(
    const float* __restrict__ partial, int nparts,
    float* __restrict__ out, float inv_n)
{
    __shared__ float s[256];
    float a = 0.0f;
    for (int i = threadIdx.x; i < nparts; i += 256) a += partial[i];
    s[threadIdx.x] = a;
    __syncthreads();
    #pragma unroll
    for (int off = 128; off > 0; off >>= 1) {
        if (threadIdx.x < off) s[threadIdx.x] += s[threadIdx.x + off];
        __syncthreads();
    }
    if (threadIdx.x == 0) out[0] = s[0] * inv_n;
}

extern "C" void kernel_launch(void* const* d_in, const int* in_sizes, int n_in,
                              void* d_out, int out_size, void* d_ws, size_t ws_size,
                              hipStream_t stream) {
    const float* targets = (const float*)d_in[0];
    const float* preds   = (const float*)d_in[1];
    // d_in[2] (decode_lengths) is unused by the reference computation.

    const int D = 512;
    const int n_rows = in_sizes[0] / D;   // 131072

    float* partial = (float*)d_ws;        // needs 2048 floats = 8 KB
    float* out = (float*)d_out;

    const int blocks = 2048;              // x 4 waves = 8192 waves, 16 rows/wave
    triplet_partial<<<blocks, 256, 0, stream>>>(targets, preds, partial, n_rows);
    triplet_final<<<1, 256, 0, stream>>>(partial, blocks, out, 1.0f / (float)n_rows);
}

// Round 4
// 93.315 us; speedup vs baseline: 1.0590x; 1.0590x over previous
//
#include <hip/hip_runtime.h>

#define MARGIN_F 0.5f
#define EPS_F 1e-12f

// Native clang vector type — __builtin_nontemporal_load requires this
// (HIP's float4 is a class and is rejected).
typedef float floatx4 __attribute__((ext_vector_type(4)));

__device__ __forceinline__ floatx4 ntload(const floatx4* p) {
    return __builtin_nontemporal_load(p);
}

// One wave (64 lanes) per row; 2 rows per iteration for memory-level
// parallelism. Each lane reads 2 float4 per array per row:
//   vec idx lane      -> floats [4*lane, 4*lane+4)
//   vec idx lane+64   -> floats [256+4*lane, 256+4*lane+4)
// 64 lanes x 16 B = 1 KB contiguous per load instruction (fully coalesced).
__global__ __launch_bounds__(256, 8) void triplet_partial(
    const float* __restrict__ targets,
    const float* __restrict__ preds,
    float* __restrict__ partial,
    int n_rows)
{
    const int lane = threadIdx.x & 63;
    const int wid  = threadIdx.x >> 6;            // wave index in block (0..3)
    const int gwave  = blockIdx.x * 4 + wid;
    const int nwaves = gridDim.x * 4;             // 8192

    float acc = 0.0f;
    for (int row0 = gwave; row0 < n_rows; row0 += 2 * nwaves) {
        const int  row1 = row0 + nwaves;
        const bool has1 = row1 < n_rows;
        const int  r1   = has1 ? row1 : row0;     // safe dup-load if tail

        const floatx4* t0 = reinterpret_cast<const floatx4*>(targets) + (size_t)row0 * 128;
        const floatx4* p0 = reinterpret_cast<const floatx4*>(preds)   + (size_t)row0 * 128;
        const floatx4* t1 = reinterpret_cast<const floatx4*>(targets) + (size_t)r1   * 128;
        const floatx4* p1 = reinterpret_cast<const floatx4*>(preds)   + (size_t)r1   * 128;

        // Issue all 8 loads up front (independent -> 8 dwordx4 in flight).
        floatx4 ta0 = ntload(t0 + lane);
        floatx4 tb0 = ntload(t0 + lane + 64);
        floatx4 pa0 = ntload(p0 + lane);
        floatx4 pb0 = ntload(p0 + lane + 64);
        floatx4 ta1 = ntload(t1 + lane);
        floatx4 tb1 = ntload(t1 + lane + 64);
        floatx4 pa1 = ntload(p1 + lane);
        floatx4 pb1 = ntload(p1 + lane + 64);

        float pp0 = pa0.x*pa0.x + pa0.y*pa0.y + pa0.z*pa0.z + pa0.w*pa0.w
                  + pb0.x*pb0.x + pb0.y*pb0.y + pb0.z*pb0.z + pb0.w*pb0.w;
        float tt0 = ta0.x*ta0.x + ta0.y*ta0.y + ta0.z*ta0.z + ta0.w*ta0.w
                  + tb0.x*tb0.x + tb0.y*tb0.y + tb0.z*tb0.z + tb0.w*tb0.w;
        float pt0 = pa0.x*ta0.x + pa0.y*ta0.y + pa0.z*ta0.z + pa0.w*ta0.w
                  + pb0.x*tb0.x + pb0.y*tb0.y + pb0.z*tb0.z + pb0.w*tb0.w;

        float pp1 = pa1.x*pa1.x + pa1.y*pa1.y + pa1.z*pa1.z + pa1.w*pa1.w
                  + pb1.x*pb1.x + pb1.y*pb1.y + pb1.z*pb1.z + pb1.w*pb1.w;
        float tt1 = ta1.x*ta1.x + ta1.y*ta1.y + ta1.z*ta1.z + ta1.w*ta1.w
                  + tb1.x*tb1.x + tb1.y*tb1.y + tb1.z*tb1.z + tb1.w*tb1.w;
        float pt1 = pa1.x*ta1.x + pa1.y*ta1.y + pa1.z*ta1.z + pa1.w*ta1.w
                  + pb1.x*tb1.x + pb1.y*tb1.y + pb1.z*tb1.z + pb1.w*tb1.w;

        // Interleaved butterfly reductions (two independent chains -> ILP).
        #pragma unroll
        for (int off = 32; off > 0; off >>= 1) {
            pp0 += __shfl_xor(pp0, off, 64);
            tt0 += __shfl_xor(tt0, off, 64);
            pt0 += __shfl_xor(pt0, off, 64);
            pp1 += __shfl_xor(pp1, off, 64);
            tt1 += __shfl_xor(tt1, off, 64);
            pt1 += __shfl_xor(pt1, off, 64);
        }

        // loss = max(margin + (pp - pt^2)/max(||neg||, eps) - pt, 0)
        {
            float pt2 = pt0 * pt0;
            float num = pp0 - pt2;
            float n2  = fmaxf(pp0 - 2.0f * pt2 + pt2 * tt0, 0.0f);
            float nrm = fmaxf(sqrtf(n2), EPS_F);
            acc += fmaxf(MARGIN_F + num / nrm - pt0, 0.0f);   // uniform across lanes
        }
        if (has1) {
            float pt2 = pt1 * pt1;
            float num = pp1 - pt2;
            float n2  = fmaxf(pp1 - 2.0f * pt2 + pt2 * tt1, 0.0f);
            float nrm = fmaxf(sqrtf(n2), EPS_F);
            acc += fmaxf(MARGIN_F + num / nrm - pt1, 0.0f);
        }
    }

    __shared__ float wsum[4];
    if (lane == 0) wsum[wid] = acc;   // all lanes hold identical acc; lane 0 writes
    __syncthreads();
    if (threadIdx.x == 0) {
        partial[blockIdx.x] = (wsum[0] + wsum[1]) + (wsum[2] + wsum[3]);
    }
}

// Deterministic single-block finish: fixed strided accumulation + fixed tree.
__global__ __launch_bounds__(256) void triplet_final(
    const float* __restrict__ partial, int nparts,
    float* __restrict__ out, float inv_n)
{
    __shared__ float s[256];
    float a = 0.0f;
    for (int i = threadIdx.x; i < nparts; i += 256) a += partial[i];
    s[threadIdx.x] = a;
    __syncthreads();
    #pragma unroll
    for (int off = 128; off > 0; off >>= 1) {
        if (threadIdx.x < off) s[threadIdx.x] += s[threadIdx.x + off];
        __syncthreads();
    }
    if (threadIdx.x == 0) out[0] = s[0] * inv_n;
}

extern "C" void kernel_launch(void* const* d_in, const int* in_sizes, int n_in,
                              void* d_out, int out_size, void* d_ws, size_t ws_size,
                              hipStream_t stream) {
    const float* targets = (const float*)d_in[0];
    const float* preds   = (const float*)d_in[1];
    // d_in[2] (decode_lengths) is unused by the reference computation.

    const int D = 512;
    const int n_rows = in_sizes[0] / D;   // 131072

    float* partial = (float*)d_ws;        // 2048 floats = 8 KB of d_ws
    float* out = (float*)d_out;

    const int blocks = 2048;              // x4 waves = 8192 waves; 16 rows/wave
    triplet_partial<<<blocks, 256, 0, stream>>>(targets, preds, partial, n_rows);
    triplet_final<<<1, 256, 0, stream>>>(partial, blocks, out, 1.0f / (float)n_rows);
}